// Round 2
// baseline (575.655 us; speedup 1.0000x reference)
//
#include <hip/hip_runtime.h>
#include <hip/hip_bf16.h>

#define DI 128
#define HS 136   // padded LDS stride in bf16 (272B = 17*16B: keeps b128 alignment, staggers banks)

typedef short short8 __attribute__((ext_vector_type(8)));
typedef float f32x4 __attribute__((ext_vector_type(4)));
typedef unsigned int uint2e __attribute__((ext_vector_type(2)));

// 4 bf16 (packed in uint2e) -> 4 fp32, 1 VALU op per value
__device__ __forceinline__ f32x4 b4tof(uint2e v) {
  f32x4 r;
  r[0] = __uint_as_float(v.x << 16);
  r[1] = __uint_as_float(v.x & 0xffff0000u);
  r[2] = __uint_as_float(v.y << 16);
  r[3] = __uint_as_float(v.y & 0xffff0000u);
  return r;
}

// ---- fused prep: deg=0 | x fp32->bf16 slice-major | weight transpose+pack ----
// slice-major layout: buf[slice][node][16 bf16] ; slice stride = N*32B (3.2MB, fits XCD L2)
__global__ __launch_bounds__(256) void k_prep(unsigned* __restrict__ deg, int N, int nb,
    const float4* __restrict__ x4, uint4* __restrict__ xb4, int tiles,
    const float* __restrict__ W1, const float* __restrict__ W2,
    const float* __restrict__ Wmu, const float* __restrict__ Wls,
    __hip_bfloat16* __restrict__ Wt) {
  int b = blockIdx.x, t = threadIdx.x;
  if (b < nb) {
    int i = b * 256 + t;
    if (i < N) deg[i] = 0u;
    return;
  }
  b -= nb;
  if (b < tiles) {
    // 64-node tile: coalesced fp32 read -> LDS transpose -> slice-major bf16 write
    __shared__ __hip_bfloat16 Hs[64][HS];
    int tile0 = b * 64;
#pragma unroll
    for (int i = 0; i < 4; ++i) {
      int k = t + i * 256;            // 1024 chunks of 8 floats
      int node = k >> 4, c8 = k & 15;
      int gn = tile0 + node;
      if (gn < N) {
        const float4* xp = x4 + (size_t)gn * 32 + c8 * 2;
        float4 a = xp[0], c = xp[1];
        __hip_bfloat162 p0 = __float22bfloat162_rn(make_float2(a.x, a.y));
        __hip_bfloat162 p1 = __float22bfloat162_rn(make_float2(a.z, a.w));
        __hip_bfloat162 p2 = __float22bfloat162_rn(make_float2(c.x, c.y));
        __hip_bfloat162 p3 = __float22bfloat162_rn(make_float2(c.z, c.w));
        uint4 o;
        o.x = *(unsigned*)&p0; o.y = *(unsigned*)&p1;
        o.z = *(unsigned*)&p2; o.w = *(unsigned*)&p3;
        *(uint4*)&Hs[node][c8 * 8] = o;
      }
    }
    __syncthreads();
#pragma unroll
    for (int i = 0; i < 2; ++i) {
      int c = t + i * 256;            // 512 chunks of 32B (node,slice)
      int row = c & 63, sl = c >> 6;
      int gn = tile0 + row;
      if (gn < N) {
        uint4* dp = xb4 + ((size_t)sl * N + gn) * 2;
        dp[0] = *(const uint4*)&Hs[row][sl * 16];
        dp[1] = *(const uint4*)&Hs[row][sl * 16 + 8];
      }
    }
    return;
  }
  b -= tiles;
  int idx = b * 256 + t;      // 3*16384
  if (idx >= 3 * 16384) return;
  int mat = idx >> 14, r = (idx >> 7) & 127, c = idx & 127;  // r=n, c=k
  float v;
  if (mat == 0)      v = W1[c * 128 + r];
  else if (mat == 1) v = W2[c * 128 + r];
  else               v = (r < 64) ? Wmu[c * 64 + r] : Wls[c * 64 + (r - 64)];
  Wt[idx] = __float2bfloat16(v);
}

// ---- deg[dst] += 1; rank[e] = old value (edge's slot within its dst row) ----
__global__ __launch_bounds__(256) void k_count(const int* __restrict__ dst,
    unsigned* __restrict__ deg, unsigned* __restrict__ rank, int E) {
  int e = blockIdx.x * 256 + threadIdx.x;
  if (e < E) rank[e] = atomicAdd(&deg[dst[e]], 1u);
}

// ---- block-local exclusive scan ----
__global__ __launch_bounds__(256) void k_scan1(const unsigned* __restrict__ deg,
    unsigned* __restrict__ part, unsigned* __restrict__ bsum, int N) {
  __shared__ unsigned s[256];
  int tid = threadIdx.x;
  int i = blockIdx.x * 256 + tid;
  unsigned v = (i < N) ? deg[i] : 0u;
  s[tid] = v;
  __syncthreads();
  for (int off = 1; off < 256; off <<= 1) {
    unsigned t = (tid >= off) ? s[tid - off] : 0u;
    __syncthreads();
    s[tid] += t;
    __syncthreads();
  }
  if (i < N) part[i] = s[tid] - v;
  if (tid == 255) bsum[blockIdx.x] = s[255];
}

// ---- single-block scan of block sums ----
__global__ __launch_bounds__(256) void k_scan2(unsigned* __restrict__ bsum, int nb) {
  __shared__ unsigned s[256];
  __shared__ unsigned carry;
  int tid = threadIdx.x;
  if (tid == 0) carry = 0u;
  __syncthreads();
  for (int base = 0; base < nb; base += 256) {
    int idx = base + tid;
    unsigned c = carry;
    unsigned v = (idx < nb) ? bsum[idx] : 0u;
    s[tid] = v;
    __syncthreads();
    for (int off = 1; off < 256; off <<= 1) {
      unsigned t = (tid >= off) ? s[tid - off] : 0u;
      __syncthreads();
      s[tid] += t;
      __syncthreads();
    }
    if (idx < nb) bsum[idx] = c + s[tid] - v;
    __syncthreads();
    if (tid == 0) carry = c + s[255];
    __syncthreads();
  }
}

// ---- rowdeg = {rowptr, deg}; dinv ----
__global__ __launch_bounds__(256) void k_scan3(const unsigned* __restrict__ part,
    const unsigned* __restrict__ bsum, const unsigned* __restrict__ deg,
    uint2e* __restrict__ rowdeg, float* __restrict__ dinv, int N) {
  int i = blockIdx.x * 256 + threadIdx.x;
  if (i >= N) return;
  unsigned d = deg[i];
  uint2e rd; rd.x = part[i] + bsum[i >> 8]; rd.y = d;
  rowdeg[i] = rd;
  dinv[i] = rsqrtf((float)(d + 1u));
}

// ---- dst-partitioned CSR fill (no atomics): csr_src[rowptr[d]+rank[e]] = src[e] ----
__global__ __launch_bounds__(256) void k_fillp(const int* __restrict__ src,
    const int* __restrict__ dst, const unsigned* __restrict__ rank,
    const uint2e* __restrict__ rowdeg, int* __restrict__ csr_src, int E, int N) {
  int p = blockIdx.x & 7;
  int b = blockIdx.x >> 3;
  int nbp = gridDim.x >> 3;
  int span = (N + 7) >> 3;
  int lo = p * span;
  int hi = lo + span; if (hi > N) hi = N;
  int chunk = (E + nbp - 1) / nbp;
  int e0 = b * chunk;
  int e1 = e0 + chunk; if (e1 > E) e1 = E;
  for (int e = e0 + threadIdx.x; e < e1; e += 256) {
    int d = dst[e];
    if (d >= lo && d < hi)
      csr_src[rowdeg[d].x + rank[e]] = src[e];
  }
}

// ---- slice-gather aggr1: bufb[s][i] = bf16( x[s][i] + sum_{j->i} x[s][j] )
// slice s = blockIdx&7 -> pinned to XCD s (round-robin dispatch); slice data
// (3.2MB) stays resident in that XCD's 4MB L2. Quad-per-node: 4 lanes x 4 bf16.
// csr/rowdeg streamed with nontemporal hint to protect slice residency.
__global__ __launch_bounds__(256) void k_aggr1(const uint2e* __restrict__ xb,
    const uint2e* __restrict__ rowdeg, const int* __restrict__ csr,
    uint2e* __restrict__ bufb, int N) {
  int s = blockIdx.x & 7;
  const uint2e* xs = xb + (size_t)s * N * 4;
  uint2e* bs = bufb + (size_t)s * N * 4;
  int lane = threadIdx.x & 63, wv = threadIdx.x >> 6;
  int q = lane >> 2, comp = lane & 3;
  int stride = (gridDim.x >> 3) * 64;
  for (int nbase = (blockIdx.x >> 3) * 64 + wv * 16; nbase < N; nbase += stride) {
    int w = nbase + q;
    bool act = (w < N);
    unsigned start = 0; int cnt = 0;
    f32x4 acc = {0.f, 0.f, 0.f, 0.f};
    if (act) {
      uint2e rd = __builtin_nontemporal_load(rowdeg + w);
      start = rd.x; cnt = (int)rd.y;
      acc = b4tof(xs[(size_t)w * 4 + comp]);   // self (in-slice, cached)
    }
    int e = 0;
    for (; e + 4 <= cnt; e += 4) {
      int i0 = __builtin_nontemporal_load(csr + start + e);
      int i1 = __builtin_nontemporal_load(csr + start + e + 1);
      int i2 = __builtin_nontemporal_load(csr + start + e + 2);
      int i3 = __builtin_nontemporal_load(csr + start + e + 3);
      uint2e v0 = xs[(size_t)i0 * 4 + comp];
      uint2e v1 = xs[(size_t)i1 * 4 + comp];
      uint2e v2 = xs[(size_t)i2 * 4 + comp];
      uint2e v3 = xs[(size_t)i3 * 4 + comp];
      acc += b4tof(v0); acc += b4tof(v1);
      acc += b4tof(v2); acc += b4tof(v3);
    }
    for (; e < cnt; ++e) {
      int i0 = __builtin_nontemporal_load(csr + start + e);
      acc += b4tof(xs[(size_t)i0 * 4 + comp]);
    }
    if (act) {
      __hip_bfloat162 p0 = __float22bfloat162_rn(make_float2(acc[0], acc[1]));
      __hip_bfloat162 p1 = __float22bfloat162_rn(make_float2(acc[2], acc[3]));
      uint2e o; o.x = *(unsigned*)&p0; o.y = *(unsigned*)&p1;
      __builtin_nontemporal_store(o, bs + (size_t)w * 4 + comp);
    }
  }
}

// ---- fused MFMA MLP: h3 = [relu(relu(BN(A@W1))@W2+b2)] @ [Wmu|Wls], bf16 io
// slice-major in/out; epilogue pre-scales rows by dinv: y_j = dinv_j * xw_j
__global__ __launch_bounds__(256, 3) void k_mlp(const __hip_bfloat16* __restrict__ Ab,
    const __hip_bfloat16* __restrict__ Wt3,   // 3 x [128][128] bf16, [n][k]
    const float* __restrict__ b1, const float* __restrict__ gamma,
    const float* __restrict__ beta, const float* __restrict__ rmean,
    const float* __restrict__ rvar, const float* __restrict__ b2,
    const float* __restrict__ dinv,
    __hip_bfloat16* __restrict__ outb, int N) {
  __shared__ __hip_bfloat16 H[64][HS];
  __shared__ __hip_bfloat16 Wt[128][HS];
  int t = threadIdx.x;
  int tile0 = blockIdx.x * 64;
  int lane = t & 63, wave = t >> 6;
  int m16 = lane & 15, quad = lane >> 4;

  {
    uint4 z = {0u, 0u, 0u, 0u};
#pragma unroll
    for (int i = 0; i < 2; ++i) {
      int c = t + i * 256;             // 512 chunks (row, slice) of 32B
      int row = c & 63, sl = c >> 6;
      int gr = tile0 + row;
      const uint4* gp = (const uint4*)(Ab + ((size_t)sl * N + gr) * 16);
      uint4 v0 = (gr < N) ? gp[0] : z;
      uint4 v1 = (gr < N) ? gp[1] : z;
      *(uint4*)&H[row][sl * 16] = v0;
      *(uint4*)&H[row][sl * 16 + 8] = v1;
    }
  }

  f32x4 acc[8];
  short8 aF[4];

  for (int l = 0; l < 3; ++l) {
    {
      int n = t >> 1, c0 = (t & 1) * 64;
      const uint4* gp = (const uint4*)(Wt3 + (size_t)l * 16384 + (size_t)n * 128 + c0);
#pragma unroll
      for (int i = 0; i < 8; ++i)
        *(uint4*)&Wt[n][c0 + i * 8] = gp[i];
    }
    __syncthreads();

#pragma unroll
    for (int ks = 0; ks < 4; ++ks)
      aF[ks] = *(const short8*)&H[wave * 16 + m16][ks * 32 + quad * 8];
#pragma unroll
    for (int nt = 0; nt < 8; ++nt) {
      f32x4 c = {0.f, 0.f, 0.f, 0.f};
#pragma unroll
      for (int ks = 0; ks < 4; ++ks) {
        short8 bF = *(const short8*)&Wt[nt * 16 + m16][ks * 32 + quad * 8];
        c = __builtin_amdgcn_mfma_f32_16x16x32_bf16(aF[ks], bF, c, 0, 0, 0);
      }
      acc[nt] = c;
    }
    __syncthreads();

    float dvr[4];
    if (l == 2) {
#pragma unroll
      for (int r = 0; r < 4; ++r) {
        int grow = tile0 + wave * 16 + quad * 4 + r;
        dvr[r] = (grow < N) ? dinv[grow] : 0.f;
      }
    }

#pragma unroll
    for (int nt = 0; nt < 8; ++nt) {
      int n = nt * 16 + m16;
      float es = 1.f, eb = 0.f;
      if (l == 0) {
        float s = gamma[n] * rsqrtf(rvar[n] + 1e-5f);
        es = s; eb = s * (b1[n] - rmean[n]) + beta[n];
      } else if (l == 1) {
        eb = b2[n];
      }
#pragma unroll
      for (int r = 0; r < 4; ++r) {
        float v = acc[nt][r] * es + eb;
        if (l < 2) v = fmaxf(v, 0.f);
        else v *= dvr[r];
        H[wave * 16 + quad * 4 + r][n] = __float2bfloat16(v);
      }
    }
  }
  __syncthreads();

  {
#pragma unroll
    for (int i = 0; i < 2; ++i) {
      int c = t + i * 256;
      int row = c & 63, sl = c >> 6;
      int gr = tile0 + row;
      if (gr < N) {
        uint4* dp = (uint4*)(outb + ((size_t)sl * N + gr) * 16);
        dp[0] = *(const uint4*)&H[row][sl * 16];
        dp[1] = *(const uint4*)&H[row][sl * 16 + 8];
      }
    }
  }
}

// ---- slice-gather GCN heads: out = bias + dinv_i * (y_i + sum y_j), y pre-scaled
__global__ __launch_bounds__(256) void k_aggr2(const uint2e* __restrict__ yb,
    const uint2e* __restrict__ rowdeg, const int* __restrict__ csr,
    const float* __restrict__ dinv,
    const float* __restrict__ bmu, const float* __restrict__ bls,
    float* __restrict__ om, float* __restrict__ ol, int N) {
  int s = blockIdx.x & 7;
  const uint2e* ys = yb + (size_t)s * N * 4;
  int lane = threadIdx.x & 63, wv = threadIdx.x >> 6;
  int q = lane >> 2, comp = lane & 3;
  const float* bsrc = (s < 4) ? bmu : bls;
  float4 bb = *(const float4*)(bsrc + (s & 3) * 16 + comp * 4);
  float* obase = (s < 4) ? om : ol;
  int ocol = (s & 3) * 16 + comp * 4;
  int stride = (gridDim.x >> 3) * 64;
  for (int nbase = (blockIdx.x >> 3) * 64 + wv * 16; nbase < N; nbase += stride) {
    int w = nbase + q;
    bool act = (w < N);
    unsigned start = 0; int cnt = 0;
    f32x4 acc = {0.f, 0.f, 0.f, 0.f};
    if (act) {
      uint2e rd = __builtin_nontemporal_load(rowdeg + w);
      start = rd.x; cnt = (int)rd.y;
      acc = b4tof(ys[(size_t)w * 4 + comp]);   // self (pre-scaled), in-slice
    }
    int e = 0;
    for (; e + 4 <= cnt; e += 4) {
      int i0 = __builtin_nontemporal_load(csr + start + e);
      int i1 = __builtin_nontemporal_load(csr + start + e + 1);
      int i2 = __builtin_nontemporal_load(csr + start + e + 2);
      int i3 = __builtin_nontemporal_load(csr + start + e + 3);
      uint2e v0 = ys[(size_t)i0 * 4 + comp];
      uint2e v1 = ys[(size_t)i1 * 4 + comp];
      uint2e v2 = ys[(size_t)i2 * 4 + comp];
      uint2e v3 = ys[(size_t)i3 * 4 + comp];
      acc += b4tof(v0); acc += b4tof(v1);
      acc += b4tof(v2); acc += b4tof(v3);
    }
    for (; e < cnt; ++e) {
      int i0 = __builtin_nontemporal_load(csr + start + e);
      acc += b4tof(ys[(size_t)i0 * 4 + comp]);
    }
    if (act) {
      float di = __builtin_nontemporal_load(dinv + w);
      f32x4 o;
      o[0] = acc[0] * di + bb.x;
      o[1] = acc[1] * di + bb.y;
      o[2] = acc[2] * di + bb.z;
      o[3] = acc[3] * di + bb.w;
      __builtin_nontemporal_store(o, (f32x4*)(obase + (size_t)w * 64 + ocol));
    }
  }
}

extern "C" void kernel_launch(void* const* d_in, const int* in_sizes, int n_in,
                              void* d_out, int out_size, void* d_ws, size_t ws_size,
                              hipStream_t stream) {
  const float* x     = (const float*)d_in[0];
  const int*   ei    = (const int*)d_in[1];
  const float* W1    = (const float*)d_in[2];
  const float* b1    = (const float*)d_in[3];
  const float* gamma = (const float*)d_in[4];
  const float* beta  = (const float*)d_in[5];
  const float* rmean = (const float*)d_in[6];
  const float* rvar  = (const float*)d_in[7];
  const float* W2    = (const float*)d_in[8];
  const float* b2    = (const float*)d_in[9];
  const float* Wmu   = (const float*)d_in[10];
  const float* bmu   = (const float*)d_in[11];
  const float* Wls   = (const float*)d_in[12];
  const float* bls   = (const float*)d_in[13];

  int N = in_sizes[0] / 128;
  int E = in_sizes[1] / 2;
  const int* src = ei;
  const int* dst = ei + E;
  int nb = (N + 255) / 256;
  int tiles = (N + 63) / 64;

  char* ws = (char*)d_ws;
  size_t off = 0;
  __hip_bfloat16* xb   = (__hip_bfloat16*)(ws + off); off += (size_t)N * DI * 2;  // slice-major; reused as y
  __hip_bfloat16* bufb = (__hip_bfloat16*)(ws + off); off += (size_t)N * DI * 2;  // slice-major
  unsigned* deg    = (unsigned*)(ws + off); off += (size_t)N * 4;
  unsigned* part   = (unsigned*)(ws + off); off += (size_t)N * 4;
  uint2e*   rowdeg = (uint2e*)(ws + off); off += (size_t)N * 8;
  float*    dinv   = (float*)(ws + off); off += (size_t)N * 4;
  unsigned* bsum   = (unsigned*)(ws + off); off += (size_t)((nb + 255) & ~255) * 4;
  __hip_bfloat16* Wt3 = (__hip_bfloat16*)(ws + off); off += 3 * 16384 * 2;
  unsigned* rank   = (unsigned*)(ws + off); off += (size_t)E * 4;
  int* csr_src     = (int*)(ws + off); off += (size_t)E * 4;

  float* om = (float*)d_out;
  float* ol = om + (size_t)N * 64;

  int prepB = nb + tiles + 192;
  int gatherB = 2048;   // 256 blocks per slice -> one XCD fully resident

  k_prep <<<prepB, 256, 0, stream>>>(deg, N, nb, (const float4*)x, (uint4*)xb,
                                     tiles, W1, W2, Wmu, Wls, Wt3);
  k_count<<<(E + 255) / 256, 256, 0, stream>>>(dst, deg, rank, E);
  k_scan1<<<nb, 256, 0, stream>>>(deg, part, bsum, N);
  k_scan2<<<1, 256, 0, stream>>>(bsum, nb);
  k_scan3<<<nb, 256, 0, stream>>>(part, bsum, deg, rowdeg, dinv, N);
  k_fillp<<<2048, 256, 0, stream>>>(src, dst, rank, rowdeg, csr_src, E, N);
  k_aggr1<<<gatherB, 256, 0, stream>>>((const uint2e*)xb, rowdeg, csr_src,
                                       (uint2e*)bufb, N);
  k_mlp  <<<tiles, 256, 0, stream>>>(bufb, Wt3, b1, gamma, beta, rmean, rvar, b2,
                                     dinv, xb /* y out, reuse */, N);
  k_aggr2<<<gatherB, 256, 0, stream>>>((const uint2e*)xb, rowdeg, csr_src,
                                       dinv, bmu, bls, om, ol, N);
}

// Round 3
// 536.177 us; speedup vs baseline: 1.0736x; 1.0736x over previous
//
#include <hip/hip_runtime.h>
#include <hip/hip_bf16.h>

#define DI 128
#define HS 136   // padded LDS stride in bf16 (272B = 17*16B: keeps b128 alignment, staggers banks)

typedef short short8 __attribute__((ext_vector_type(8)));
typedef float f32x4 __attribute__((ext_vector_type(4)));
typedef unsigned int uint2e __attribute__((ext_vector_type(2)));

// 4 bf16 (packed in uint2e) -> 4 fp32, 1 VALU op per value
__device__ __forceinline__ f32x4 b4tof(uint2e v) {
  f32x4 r;
  r[0] = __uint_as_float(v.x << 16);
  r[1] = __uint_as_float(v.x & 0xffff0000u);
  r[2] = __uint_as_float(v.y << 16);
  r[3] = __uint_as_float(v.y & 0xffff0000u);
  return r;
}

// ---- fused prep: deg=0 | x fp32->bf16 slice-major | weight transpose+pack ----
// slice-major layout: buf[slice][node][16 bf16] ; slice stride = N*32B (3.2MB, fits XCD L2)
__global__ __launch_bounds__(256) void k_prep(unsigned* __restrict__ deg, int N, int nb,
    const float4* __restrict__ x4, uint4* __restrict__ xb4, int tiles,
    const float* __restrict__ W1, const float* __restrict__ W2,
    const float* __restrict__ Wmu, const float* __restrict__ Wls,
    __hip_bfloat16* __restrict__ Wt) {
  int b = blockIdx.x, t = threadIdx.x;
  if (b < nb) {
    int i = b * 256 + t;
    if (i < N) deg[i] = 0u;
    return;
  }
  b -= nb;
  if (b < tiles) {
    __shared__ __hip_bfloat16 Hs[64][HS];
    int tile0 = b * 64;
#pragma unroll
    for (int i = 0; i < 4; ++i) {
      int k = t + i * 256;            // 1024 chunks of 8 floats
      int node = k >> 4, c8 = k & 15;
      int gn = tile0 + node;
      if (gn < N) {
        const float4* xp = x4 + (size_t)gn * 32 + c8 * 2;
        float4 a = xp[0], c = xp[1];
        __hip_bfloat162 p0 = __float22bfloat162_rn(make_float2(a.x, a.y));
        __hip_bfloat162 p1 = __float22bfloat162_rn(make_float2(a.z, a.w));
        __hip_bfloat162 p2 = __float22bfloat162_rn(make_float2(c.x, c.y));
        __hip_bfloat162 p3 = __float22bfloat162_rn(make_float2(c.z, c.w));
        uint4 o;
        o.x = *(unsigned*)&p0; o.y = *(unsigned*)&p1;
        o.z = *(unsigned*)&p2; o.w = *(unsigned*)&p3;
        *(uint4*)&Hs[node][c8 * 8] = o;
      }
    }
    __syncthreads();
#pragma unroll
    for (int i = 0; i < 2; ++i) {
      int c = t + i * 256;            // 512 chunks of 32B (node,slice)
      int row = c & 63, sl = c >> 6;
      int gn = tile0 + row;
      if (gn < N) {
        uint4* dp = xb4 + ((size_t)sl * N + gn) * 2;
        dp[0] = *(const uint4*)&Hs[row][sl * 16];
        dp[1] = *(const uint4*)&Hs[row][sl * 16 + 8];
      }
    }
    return;
  }
  b -= tiles;
  int idx = b * 256 + t;      // 3*16384
  if (idx >= 3 * 16384) return;
  int mat = idx >> 14, r = (idx >> 7) & 127, c = idx & 127;  // r=n, c=k
  float v;
  if (mat == 0)      v = W1[c * 128 + r];
  else if (mat == 1) v = W2[c * 128 + r];
  else               v = (r < 64) ? Wmu[c * 64 + r] : Wls[c * 64 + (r - 64)];
  Wt[idx] = __float2bfloat16(v);
}

// ---- deg[dst] += 1; rank[e] = old value ----
__global__ __launch_bounds__(256) void k_count(const int* __restrict__ dst,
    unsigned* __restrict__ deg, unsigned* __restrict__ rank, int E) {
  int e = blockIdx.x * 256 + threadIdx.x;
  if (e < E) rank[e] = atomicAdd(&deg[dst[e]], 1u);
}

// ---- block-local exclusive scan ----
__global__ __launch_bounds__(256) void k_scan1(const unsigned* __restrict__ deg,
    unsigned* __restrict__ part, unsigned* __restrict__ bsum, int N) {
  __shared__ unsigned s[256];
  int tid = threadIdx.x;
  int i = blockIdx.x * 256 + tid;
  unsigned v = (i < N) ? deg[i] : 0u;
  s[tid] = v;
  __syncthreads();
  for (int off = 1; off < 256; off <<= 1) {
    unsigned t = (tid >= off) ? s[tid - off] : 0u;
    __syncthreads();
    s[tid] += t;
    __syncthreads();
  }
  if (i < N) part[i] = s[tid] - v;
  if (tid == 255) bsum[blockIdx.x] = s[255];
}

// ---- single-block scan of block sums ----
__global__ __launch_bounds__(256) void k_scan2(unsigned* __restrict__ bsum, int nb) {
  __shared__ unsigned s[256];
  __shared__ unsigned carry;
  int tid = threadIdx.x;
  if (tid == 0) carry = 0u;
  __syncthreads();
  for (int base = 0; base < nb; base += 256) {
    int idx = base + tid;
    unsigned c = carry;
    unsigned v = (idx < nb) ? bsum[idx] : 0u;
    s[tid] = v;
    __syncthreads();
    for (int off = 1; off < 256; off <<= 1) {
      unsigned t = (tid >= off) ? s[tid - off] : 0u;
      __syncthreads();
      s[tid] += t;
      __syncthreads();
    }
    if (idx < nb) bsum[idx] = c + s[tid] - v;
    __syncthreads();
    if (tid == 0) carry = c + s[255];
    __syncthreads();
  }
}

// ---- rowdeg = {rowptr, deg}; dinv ----
__global__ __launch_bounds__(256) void k_scan3(const unsigned* __restrict__ part,
    const unsigned* __restrict__ bsum, const unsigned* __restrict__ deg,
    uint2e* __restrict__ rowdeg, float* __restrict__ dinv, int N) {
  int i = blockIdx.x * 256 + threadIdx.x;
  if (i >= N) return;
  unsigned d = deg[i];
  uint2e rd; rd.x = part[i] + bsum[i >> 8]; rd.y = d;
  rowdeg[i] = rd;
  dinv[i] = rsqrtf((float)(d + 1u));
}

// ---- dst-partitioned CSR fill (no atomics) ----
__global__ __launch_bounds__(256) void k_fillp(const int* __restrict__ src,
    const int* __restrict__ dst, const unsigned* __restrict__ rank,
    const uint2e* __restrict__ rowdeg, int* __restrict__ csr_src, int E, int N) {
  int p = blockIdx.x & 7;
  int b = blockIdx.x >> 3;
  int nbp = gridDim.x >> 3;
  int span = (N + 7) >> 3;
  int lo = p * span;
  int hi = lo + span; if (hi > N) hi = N;
  int chunk = (E + nbp - 1) / nbp;
  int e0 = b * chunk;
  int e1 = e0 + chunk; if (e1 > E) e1 = E;
  for (int e = e0 + threadIdx.x; e < e1; e += 256) {
    int d = dst[e];
    if (d >= lo && d < hi)
      csr_src[rowdeg[d].x + rank[e]] = src[e];
  }
}

// ---- slice gather, 4 nodes per wave ----
// lane = 16*nd + 4*et + comp. One gather instr = 4 nodes x 4 edges x 32B.
// csr idx wave-batched (16/node in node's 16 lanes, distributed via shfl).
// et-reduction (shfl_xor 4,8) reduces all 4 nodes in parallel.
// Pipeline: next group's rowdeg issued before gathers, csr/self after.
__global__ __launch_bounds__(256) void k_aggr1(const uint2e* __restrict__ xb,
    const uint2e* __restrict__ rowdeg, const int* __restrict__ csr,
    uint2e* __restrict__ bufb, int N) {
  int s = blockIdx.x & 7;
  const uint2e* xs = xb + (size_t)s * N * 4;
  uint2e* bs = bufb + (size_t)s * N * 4;
  int lane = threadIdx.x & 63, wv = threadIdx.x >> 6;
  int nd = lane >> 4, et = (lane >> 2) & 3, comp = lane & 3, l16 = lane & 15;
  int ngroups = (N + 3) >> 2;
  int gstride = (gridDim.x >> 3) * 4;
  int g = (blockIdx.x >> 3) * 4 + wv;
  if (g >= ngroups) return;

  int w = g * 4 + nd;
  uint2e rd = {0u, 0u};
  if (w < N) rd = __builtin_nontemporal_load(rowdeg + w);
  int idx = (l16 < (int)rd.y) ? __builtin_nontemporal_load(csr + rd.x + l16) : 0;
  uint2e sv = {0u, 0u};
  if (et == 0 && w < N) sv = xs[(unsigned)w * 4u + comp];

  while (true) {
    int gn = g + gstride;
    int wn = gn * 4 + nd;
    uint2e rdn = {0u, 0u};
    if (gn < ngroups && wn < N) rdn = __builtin_nontemporal_load(rowdeg + wn);

    unsigned start = rd.x;
    int cnt = (int)rd.y;
    f32x4 acc = b4tof(sv);           // self on et==0 lanes, 0 elsewhere
    int base = 0;
    int curidx = idx;
    while (true) {
#pragma unroll
      for (int j = 0; j < 4; ++j) {
        int e = base + j * 4 + et;
        if (!__any(e < cnt)) break;
        int se = __shfl(curidx, (lane & 48) + j * 4 + et);
        uint2e v = xs[(unsigned)se * 4u + comp];
        bool val = e < cnt;
        v.x = val ? v.x : 0u;
        v.y = val ? v.y : 0u;
        acc += b4tof(v);
      }
      base += 16;
      if (!__any(base < cnt)) break;
      curidx = (l16 + base < cnt)
             ? __builtin_nontemporal_load(csr + start + base + l16) : 0;
    }

    // prefetch next group's csr batch + self (rdn ready by now)
    int idxn = 0;
    uint2e svn = {0u, 0u};
    if (gn < ngroups) {
      idxn = (l16 < (int)rdn.y)
           ? __builtin_nontemporal_load(csr + rdn.x + l16) : 0;
      if (et == 0 && wn < N) svn = xs[(unsigned)wn * 4u + comp];
    }

#pragma unroll
    for (int k = 0; k < 4; ++k) {
      acc[k] += __shfl_xor(acc[k], 4);
      acc[k] += __shfl_xor(acc[k], 8);
    }
    if (et == 0 && w < N) {
      __hip_bfloat162 p0 = __float22bfloat162_rn(make_float2(acc[0], acc[1]));
      __hip_bfloat162 p1 = __float22bfloat162_rn(make_float2(acc[2], acc[3]));
      uint2e o; o.x = *(unsigned*)&p0; o.y = *(unsigned*)&p1;
      __builtin_nontemporal_store(o, bs + (unsigned)w * 4u + comp);
    }
    if (gn >= ngroups) break;
    g = gn; w = wn; rd = rdn; idx = idxn; sv = svn;
  }
}

// ---- fused MFMA MLP (slice-major io, dinv pre-scale in epilogue) ----
__global__ __launch_bounds__(256, 3) void k_mlp(const __hip_bfloat16* __restrict__ Ab,
    const __hip_bfloat16* __restrict__ Wt3,   // 3 x [128][128] bf16, [n][k]
    const float* __restrict__ b1, const float* __restrict__ gamma,
    const float* __restrict__ beta, const float* __restrict__ rmean,
    const float* __restrict__ rvar, const float* __restrict__ b2,
    const float* __restrict__ dinv,
    __hip_bfloat16* __restrict__ outb, int N) {
  __shared__ __hip_bfloat16 H[64][HS];
  __shared__ __hip_bfloat16 Wt[128][HS];
  int t = threadIdx.x;
  int tile0 = blockIdx.x * 64;
  int lane = t & 63, wave = t >> 6;
  int m16 = lane & 15, quad = lane >> 4;

  {
    uint4 z = {0u, 0u, 0u, 0u};
#pragma unroll
    for (int i = 0; i < 2; ++i) {
      int c = t + i * 256;             // 512 chunks (row, slice) of 32B
      int row = c & 63, sl = c >> 6;
      int gr = tile0 + row;
      const uint4* gp = (const uint4*)(Ab + ((size_t)sl * N + gr) * 16);
      uint4 v0 = (gr < N) ? gp[0] : z;
      uint4 v1 = (gr < N) ? gp[1] : z;
      *(uint4*)&H[row][sl * 16] = v0;
      *(uint4*)&H[row][sl * 16 + 8] = v1;
    }
  }

  f32x4 acc[8];
  short8 aF[4];

  for (int l = 0; l < 3; ++l) {
    {
      int n = t >> 1, c0 = (t & 1) * 64;
      const uint4* gp = (const uint4*)(Wt3 + (size_t)l * 16384 + (size_t)n * 128 + c0);
#pragma unroll
      for (int i = 0; i < 8; ++i)
        *(uint4*)&Wt[n][c0 + i * 8] = gp[i];
    }
    __syncthreads();

#pragma unroll
    for (int ks = 0; ks < 4; ++ks)
      aF[ks] = *(const short8*)&H[wave * 16 + m16][ks * 32 + quad * 8];
#pragma unroll
    for (int nt = 0; nt < 8; ++nt) {
      f32x4 c = {0.f, 0.f, 0.f, 0.f};
#pragma unroll
      for (int ks = 0; ks < 4; ++ks) {
        short8 bF = *(const short8*)&Wt[nt * 16 + m16][ks * 32 + quad * 8];
        c = __builtin_amdgcn_mfma_f32_16x16x32_bf16(aF[ks], bF, c, 0, 0, 0);
      }
      acc[nt] = c;
    }
    __syncthreads();

    float dvr[4];
    if (l == 2) {
#pragma unroll
      for (int r = 0; r < 4; ++r) {
        int grow = tile0 + wave * 16 + quad * 4 + r;
        dvr[r] = (grow < N) ? dinv[grow] : 0.f;
      }
    }

#pragma unroll
    for (int nt = 0; nt < 8; ++nt) {
      int n = nt * 16 + m16;
      float es = 1.f, eb = 0.f;
      if (l == 0) {
        float s = gamma[n] * rsqrtf(rvar[n] + 1e-5f);
        es = s; eb = s * (b1[n] - rmean[n]) + beta[n];
      } else if (l == 1) {
        eb = b2[n];
      }
#pragma unroll
      for (int r = 0; r < 4; ++r) {
        float v = acc[nt][r] * es + eb;
        if (l < 2) v = fmaxf(v, 0.f);
        else v *= dvr[r];
        H[wave * 16 + quad * 4 + r][n] = __float2bfloat16(v);
      }
    }
  }
  __syncthreads();

  {
#pragma unroll
    for (int i = 0; i < 2; ++i) {
      int c = t + i * 256;
      int row = c & 63, sl = c >> 6;
      int gr = tile0 + row;
      if (gr < N) {
        uint4* dp = (uint4*)(outb + ((size_t)sl * N + gr) * 16);
        dp[0] = *(const uint4*)&H[row][sl * 16];
        dp[1] = *(const uint4*)&H[row][sl * 16 + 8];
      }
    }
  }
}

// ---- slice gather GCN heads: out = bias + dinv_i * (y_i + sum y_j), y pre-scaled ----
__global__ __launch_bounds__(256) void k_aggr2(const uint2e* __restrict__ yb,
    const uint2e* __restrict__ rowdeg, const int* __restrict__ csr,
    const float* __restrict__ dinv,
    const float* __restrict__ bmu, const float* __restrict__ bls,
    float* __restrict__ om, float* __restrict__ ol, int N) {
  int s = blockIdx.x & 7;
  const uint2e* ys = yb + (size_t)s * N * 4;
  const float* bsrc = (s < 4) ? bmu : bls;
  float* obase = (s < 4) ? om : ol;
  int lane = threadIdx.x & 63, wv = threadIdx.x >> 6;
  int nd = lane >> 4, et = (lane >> 2) & 3, comp = lane & 3, l16 = lane & 15;
  float4 bb = *(const float4*)(bsrc + (s & 3) * 16 + comp * 4);
  int ocol = (s & 3) * 16 + comp * 4;
  int ngroups = (N + 3) >> 2;
  int gstride = (gridDim.x >> 3) * 4;
  int g = (blockIdx.x >> 3) * 4 + wv;
  if (g >= ngroups) return;

  int w = g * 4 + nd;
  uint2e rd = {0u, 0u};
  if (w < N) rd = __builtin_nontemporal_load(rowdeg + w);
  int idx = (l16 < (int)rd.y) ? __builtin_nontemporal_load(csr + rd.x + l16) : 0;
  uint2e sv = {0u, 0u};
  float di = 0.f;
  if (et == 0 && w < N) {
    sv = ys[(unsigned)w * 4u + comp];
    di = __builtin_nontemporal_load(dinv + w);
  }

  while (true) {
    int gn = g + gstride;
    int wn = gn * 4 + nd;
    uint2e rdn = {0u, 0u};
    if (gn < ngroups && wn < N) rdn = __builtin_nontemporal_load(rowdeg + wn);

    unsigned start = rd.x;
    int cnt = (int)rd.y;
    f32x4 acc = b4tof(sv);           // self (pre-scaled) on et==0 lanes
    int base = 0;
    int curidx = idx;
    while (true) {
#pragma unroll
      for (int j = 0; j < 4; ++j) {
        int e = base + j * 4 + et;
        if (!__any(e < cnt)) break;
        int se = __shfl(curidx, (lane & 48) + j * 4 + et);
        uint2e v = ys[(unsigned)se * 4u + comp];
        bool val = e < cnt;
        v.x = val ? v.x : 0u;
        v.y = val ? v.y : 0u;
        acc += b4tof(v);
      }
      base += 16;
      if (!__any(base < cnt)) break;
      curidx = (l16 + base < cnt)
             ? __builtin_nontemporal_load(csr + start + base + l16) : 0;
    }

    int idxn = 0;
    uint2e svn = {0u, 0u};
    float din = 0.f;
    if (gn < ngroups) {
      idxn = (l16 < (int)rdn.y)
           ? __builtin_nontemporal_load(csr + rdn.x + l16) : 0;
      if (et == 0 && wn < N) {
        svn = ys[(unsigned)wn * 4u + comp];
        din = __builtin_nontemporal_load(dinv + wn);
      }
    }

#pragma unroll
    for (int k = 0; k < 4; ++k) {
      acc[k] += __shfl_xor(acc[k], 4);
      acc[k] += __shfl_xor(acc[k], 8);
    }
    if (et == 0 && w < N) {
      f32x4 o;
      o[0] = acc[0] * di + bb.x;
      o[1] = acc[1] * di + bb.y;
      o[2] = acc[2] * di + bb.z;
      o[3] = acc[3] * di + bb.w;
      __builtin_nontemporal_store(o, (f32x4*)(obase + (size_t)w * 64 + ocol));
    }
    if (gn >= ngroups) break;
    g = gn; w = wn; rd = rdn; idx = idxn; sv = svn; di = din;
  }
}

extern "C" void kernel_launch(void* const* d_in, const int* in_sizes, int n_in,
                              void* d_out, int out_size, void* d_ws, size_t ws_size,
                              hipStream_t stream) {
  const float* x     = (const float*)d_in[0];
  const int*   ei    = (const int*)d_in[1];
  const float* W1    = (const float*)d_in[2];
  const float* b1    = (const float*)d_in[3];
  const float* gamma = (const float*)d_in[4];
  const float* beta  = (const float*)d_in[5];
  const float* rmean = (const float*)d_in[6];
  const float* rvar  = (const float*)d_in[7];
  const float* W2    = (const float*)d_in[8];
  const float* b2    = (const float*)d_in[9];
  const float* Wmu   = (const float*)d_in[10];
  const float* bmu   = (const float*)d_in[11];
  const float* Wls   = (const float*)d_in[12];
  const float* bls   = (const float*)d_in[13];

  int N = in_sizes[0] / 128;
  int E = in_sizes[1] / 2;
  const int* src = ei;
  const int* dst = ei + E;
  int nb = (N + 255) / 256;
  int tiles = (N + 63) / 64;

  char* ws = (char*)d_ws;
  size_t off = 0;
  __hip_bfloat16* xb   = (__hip_bfloat16*)(ws + off); off += (size_t)N * DI * 2;  // slice-major; reused as y
  __hip_bfloat16* bufb = (__hip_bfloat16*)(ws + off); off += (size_t)N * DI * 2;  // slice-major
  unsigned* deg    = (unsigned*)(ws + off); off += (size_t)N * 4;
  unsigned* part   = (unsigned*)(ws + off); off += (size_t)N * 4;
  uint2e*   rowdeg = (uint2e*)(ws + off); off += (size_t)N * 8;
  float*    dinv   = (float*)(ws + off); off += (size_t)N * 4;
  unsigned* bsum   = (unsigned*)(ws + off); off += (size_t)((nb + 255) & ~255) * 4;
  __hip_bfloat16* Wt3 = (__hip_bfloat16*)(ws + off); off += 3 * 16384 * 2;
  unsigned* rank   = (unsigned*)(ws + off); off += (size_t)E * 4;
  int* csr_src     = (int*)(ws + off); off += (size_t)E * 4;

  float* om = (float*)d_out;
  float* ol = om + (size_t)N * 64;

  int prepB = nb + tiles + 192;
  int gatherB = 2048;   // 256 blocks/slice -> slice pinned to one XCD

  k_prep <<<prepB, 256, 0, stream>>>(deg, N, nb, (const float4*)x, (uint4*)xb,
                                     tiles, W1, W2, Wmu, Wls, Wt3);
  k_count<<<(E + 255) / 256, 256, 0, stream>>>(dst, deg, rank, E);
  k_scan1<<<nb, 256, 0, stream>>>(deg, part, bsum, N);
  k_scan2<<<1, 256, 0, stream>>>(bsum, nb);
  k_scan3<<<nb, 256, 0, stream>>>(part, bsum, deg, rowdeg, dinv, N);
  k_fillp<<<2048, 256, 0, stream>>>(src, dst, rank, rowdeg, csr_src, E, N);
  k_aggr1<<<gatherB, 256, 0, stream>>>((const uint2e*)xb, rowdeg, csr_src,
                                       (uint2e*)bufb, N);
  k_mlp  <<<tiles, 256, 0, stream>>>(bufb, Wt3, b1, gamma, beta, rmean, rvar, b2,
                                     dinv, xb /* y out, reuse */, N);
  k_aggr2<<<gatherB, 256, 0, stream>>>((const uint2e*)xb, rowdeg, csr_src,
                                       dinv, bmu, bls, om, ol, N);
}

// Round 5
// 415.455 us; speedup vs baseline: 1.3856x; 1.2906x over previous
//
#include <hip/hip_runtime.h>
#include <hip/hip_bf16.h>

#define DI 128
#define HS 136   // padded LDS stride in bf16 (272B = 17*16B: keeps b128 alignment, staggers banks)

typedef short short8 __attribute__((ext_vector_type(8)));
typedef float f32x4 __attribute__((ext_vector_type(4)));
typedef unsigned int uint2e __attribute__((ext_vector_type(2)));
typedef int int2e __attribute__((ext_vector_type(2)));
typedef int int4e __attribute__((ext_vector_type(4)));

// 4 bf16 (packed in uint2e) -> 4 fp32, 1 VALU op per value
__device__ __forceinline__ f32x4 b4tof(uint2e v) {
  f32x4 r;
  r[0] = __uint_as_float(v.x << 16);
  r[1] = __uint_as_float(v.x & 0xffff0000u);
  r[2] = __uint_as_float(v.y << 16);
  r[3] = __uint_as_float(v.y & 0xffff0000u);
  return r;
}

// ---- fused prep: deg=0 | x fp32->bf16 (row-major) | weight transpose+pack ----
__global__ __launch_bounds__(256) void k_prep(unsigned* __restrict__ deg, int N, int nb,
    const float4* __restrict__ x4, uint4* __restrict__ xb4, int tot8, int cvtB,
    const float* __restrict__ W1, const float* __restrict__ W2,
    const float* __restrict__ Wmu, const float* __restrict__ Wls,
    __hip_bfloat16* __restrict__ Wt) {
  int b = blockIdx.x, t = threadIdx.x;
  if (b < nb) {
    int i = b * 256 + t;
    if (i < N) deg[i] = 0u;
    return;
  }
  b -= nb;
  if (b < cvtB) {
    int i = b * 256 + t;
    if (i >= tot8) return;
    float4 a = x4[2 * i], c = x4[2 * i + 1];
    __hip_bfloat162 p0 = __float22bfloat162_rn(make_float2(a.x, a.y));
    __hip_bfloat162 p1 = __float22bfloat162_rn(make_float2(a.z, a.w));
    __hip_bfloat162 p2 = __float22bfloat162_rn(make_float2(c.x, c.y));
    __hip_bfloat162 p3 = __float22bfloat162_rn(make_float2(c.z, c.w));
    uint4 o;
    o.x = *(unsigned*)&p0; o.y = *(unsigned*)&p1;
    o.z = *(unsigned*)&p2; o.w = *(unsigned*)&p3;
    xb4[i] = o;
    return;
  }
  b -= cvtB;
  int idx = b * 256 + t;      // 3*16384
  if (idx >= 3 * 16384) return;
  int mat = idx >> 14, r = (idx >> 7) & 127, c = idx & 127;  // r=n, c=k
  float v;
  if (mat == 0)      v = W1[c * 128 + r];
  else if (mat == 1) v = W2[c * 128 + r];
  else               v = (r < 64) ? Wmu[c * 64 + r] : Wls[c * 64 + (r - 64)];
  Wt[idx] = __float2bfloat16(v);
}

// ---- deg[dst] += 1; rank[e] = old (u16, max random degree << 65536) ----
// 2 edges/thread: int2 stream read, two atomics, one packed u32 rank store.
__global__ __launch_bounds__(256) void k_count(const int2e* __restrict__ dst2,
    unsigned* __restrict__ deg, unsigned* __restrict__ rankpk, int E2) {
  int i = blockIdx.x * 256 + threadIdx.x;
  if (i >= E2) return;
  int2e d = __builtin_nontemporal_load(dst2 + i);
  unsigned r0 = atomicAdd(&deg[d.x], 1u);
  unsigned r1 = atomicAdd(&deg[d.y], 1u);
  __builtin_nontemporal_store((r0 & 0xffffu) | (r1 << 16), rankpk + i);
}

// ---- block-local exclusive scan ----
__global__ __launch_bounds__(256) void k_scan1(const unsigned* __restrict__ deg,
    unsigned* __restrict__ part, unsigned* __restrict__ bsum, int N) {
  __shared__ unsigned s[256];
  int tid = threadIdx.x;
  int i = blockIdx.x * 256 + tid;
  unsigned v = (i < N) ? deg[i] : 0u;
  s[tid] = v;
  __syncthreads();
  for (int off = 1; off < 256; off <<= 1) {
    unsigned t = (tid >= off) ? s[tid - off] : 0u;
    __syncthreads();
    s[tid] += t;
    __syncthreads();
  }
  if (i < N) part[i] = s[tid] - v;
  if (tid == 255) bsum[blockIdx.x] = s[255];
}

// ---- single-block scan of block sums ----
__global__ __launch_bounds__(256) void k_scan2(unsigned* __restrict__ bsum, int nb) {
  __shared__ unsigned s[256];
  __shared__ unsigned carry;
  int tid = threadIdx.x;
  if (tid == 0) carry = 0u;
  __syncthreads();
  for (int base = 0; base < nb; base += 256) {
    int idx = base + tid;
    unsigned c = carry;
    unsigned v = (idx < nb) ? bsum[idx] : 0u;
    s[tid] = v;
    __syncthreads();
    for (int off = 1; off < 256; off <<= 1) {
      unsigned t = (tid >= off) ? s[tid - off] : 0u;
      __syncthreads();
      s[tid] += t;
      __syncthreads();
    }
    if (idx < nb) bsum[idx] = c + s[tid] - v;
    __syncthreads();
    if (tid == 0) carry = c + s[255];
    __syncthreads();
  }
}

// ---- rowptr; dinv ----
__global__ __launch_bounds__(256) void k_scan3(const unsigned* __restrict__ part,
    const unsigned* __restrict__ bsum, const unsigned* __restrict__ deg,
    unsigned* __restrict__ rowptr, float* __restrict__ dinv, int N) {
  int i = blockIdx.x * 256 + threadIdx.x;
  if (i >= N) return;
  rowptr[i] = part[i] + bsum[i >> 8];
  dinv[i] = rsqrtf((float)(deg[i] + 1u));
}

// ---- dst-partitioned CSR fill (no atomics): csr_src[rowptr[d]+rank[e]] = src[e]
// partition p owns dst range; its csr slice (~800KB) stays hot in L2 so 64B
// lines fill completely before writeback. dst is the only 8x-replicated
// stream -> int4 vectorized.
__global__ __launch_bounds__(256) void k_fillp(const int* __restrict__ src,
    const int4e* __restrict__ dst4, const unsigned short* __restrict__ rank,
    const unsigned* __restrict__ rowptr, int* __restrict__ csr_src, int E, int N) {
  int p = blockIdx.x & 7;
  int b = blockIdx.x >> 3;
  int nbp = gridDim.x >> 3;
  int span = (N + 7) >> 3;
  int lo = p * span;
  int hi = lo + span; if (hi > N) hi = N;
  int chunk = (((E + nbp - 1) / nbp) + 3) & ~3;   // multiple of 4
  int e0 = b * chunk;
  int e1 = e0 + chunk; if (e1 > E) e1 = E;       // E is a multiple of 4
  for (int e = e0 + threadIdx.x * 4; e < e1; e += 1024) {
    int4e d = __builtin_nontemporal_load(dst4 + (e >> 2));
    if (d.x >= lo && d.x < hi) csr_src[rowptr[d.x] + rank[e]]     = src[e];
    if (d.y >= lo && d.y < hi) csr_src[rowptr[d.y] + rank[e + 1]] = src[e + 1];
    if (d.z >= lo && d.z < hi) csr_src[rowptr[d.z] + rank[e + 2]] = src[e + 2];
    if (d.w >= lo && d.w < hi) csr_src[rowptr[d.w] + rank[e + 3]] = src[e + 3];
  }
}

// ---- aggr1: bufb[i] = bf16( x[i] + sum_{j->i} x[j] )
// One wave per node; 8B/lane, 2 edges per load instr (lanes 0-31 even edge,
// 32-63 odd edge). Full 16-edge bursts + ONE predicated 16-edge burst for the
// tail (shfl index clamped to m-1 -> duplicate loads coalesce; values masked).
__global__ __launch_bounds__(256) void k_aggr1(const uint2e* __restrict__ xb,
    const unsigned* __restrict__ rowptr, const unsigned* __restrict__ deg,
    const int* __restrict__ csr, uint2e* __restrict__ bufb, int N) {
  int gid = blockIdx.x * 256 + threadIdx.x;
  int w = gid >> 6, lane = gid & 63;
  if (w >= N) return;
  int h = lane >> 5, c4 = lane & 31;
  unsigned rowbase = (unsigned)w * 32u + (unsigned)c4;
  f32x4 a0 = {0.f, 0.f, 0.f, 0.f}, a1 = {0.f, 0.f, 0.f, 0.f};
  uint2e sv = xb[rowbase];
  if (h == 0) a0 = b4tof(sv);          // self term once
  unsigned start = rowptr[w];
  int cnt = (int)deg[w];
  for (int base = 0; base < cnt; base += 64) {
    int rem = cnt - base;
    int m = rem < 64 ? rem : 64;
    int idx = 0;
    if (lane < m)
      idx = __builtin_nontemporal_load(csr + start + base + lane);
    int j = 0;
    for (; j + 16 <= m; j += 16) {     // full bursts: 8 loads in flight
      uint2e v[8];
#pragma unroll
      for (int u = 0; u < 8; ++u) {
        int s = __shfl(idx, j + 2 * u + h);
        v[u] = xb[(unsigned)s * 32u + (unsigned)c4];
      }
#pragma unroll
      for (int u = 0; u < 8; ++u) {
        if (u & 1) a1 += b4tof(v[u]); else a0 += b4tof(v[u]);
      }
    }
    if (j < m) {                        // one predicated burst for the tail
      uint2e v[8];
#pragma unroll
      for (int u = 0; u < 8; ++u) {
        int ee = j + 2 * u + h;
        int s = __shfl(idx, ee < m ? ee : (m - 1));
        v[u] = xb[(unsigned)s * 32u + (unsigned)c4];
      }
#pragma unroll
      for (int u = 0; u < 8; ++u) {
        int ee = j + 2 * u + h;
        bool val = ee < m;
        v[u].x = val ? v[u].x : 0u;
        v[u].y = val ? v[u].y : 0u;
        if (u & 1) a1 += b4tof(v[u]); else a0 += b4tof(v[u]);
      }
    }
  }
  a0 += a1;
#pragma unroll
  for (int k = 0; k < 4; ++k) a0[k] += __shfl_xor(a0[k], 32);
  if (h == 0) {
    __hip_bfloat162 p0 = __float22bfloat162_rn(make_float2(a0[0], a0[1]));
    __hip_bfloat162 p1 = __float22bfloat162_rn(make_float2(a0[2], a0[3]));
    uint2e o;
    o.x = *(unsigned*)&p0; o.y = *(unsigned*)&p1;
    __builtin_nontemporal_store(o, bufb + rowbase);
  }
}

// ---- fused MFMA MLP: h3 = [relu(relu(BN(A@W1))@W2+b2)] @ [Wmu|Wls], bf16 io
// epilogue of last layer pre-scales rows by dinv: y_j = dinv_j * xw_j
__global__ __launch_bounds__(256, 3) void k_mlp(const __hip_bfloat16* __restrict__ Ab,
    const __hip_bfloat16* __restrict__ Wt3,   // 3 x [128][128] bf16, [n][k]
    const float* __restrict__ b1, const float* __restrict__ gamma,
    const float* __restrict__ beta, const float* __restrict__ rmean,
    const float* __restrict__ rvar, const float* __restrict__ b2,
    const float* __restrict__ dinv,
    __hip_bfloat16* __restrict__ outb, int N) {
  __shared__ __hip_bfloat16 H[64][HS];
  __shared__ __hip_bfloat16 Wt[128][HS];
  int t = threadIdx.x;
  int tile0 = blockIdx.x * 64;
  int lane = t & 63, wave = t >> 6;
  int m16 = lane & 15, quad = lane >> 4;

  {
    int row = t >> 2, c0 = (t & 3) * 32;
    int gr = tile0 + row;
    uint4 z = {0u, 0u, 0u, 0u};
    const uint4* gp = (const uint4*)(Ab + (size_t)gr * DI + c0);
#pragma unroll
    for (int i = 0; i < 4; ++i) {
      uint4 v = (gr < N) ? gp[i] : z;
      *(uint4*)&H[row][c0 + i * 8] = v;
    }
  }

  f32x4 acc[8];
  short8 aF[4];

  for (int l = 0; l < 3; ++l) {
    {
      int n = t >> 1, c0 = (t & 1) * 64;
      const uint4* gp = (const uint4*)(Wt3 + (size_t)l * 16384 + (size_t)n * 128 + c0);
#pragma unroll
      for (int i = 0; i < 8; ++i)
        *(uint4*)&Wt[n][c0 + i * 8] = gp[i];
    }
    __syncthreads();

#pragma unroll
    for (int ks = 0; ks < 4; ++ks)
      aF[ks] = *(const short8*)&H[wave * 16 + m16][ks * 32 + quad * 8];
#pragma unroll
    for (int nt = 0; nt < 8; ++nt) {
      f32x4 c = {0.f, 0.f, 0.f, 0.f};
#pragma unroll
      for (int ks = 0; ks < 4; ++ks) {
        short8 bF = *(const short8*)&Wt[nt * 16 + m16][ks * 32 + quad * 8];
        c = __builtin_amdgcn_mfma_f32_16x16x32_bf16(aF[ks], bF, c, 0, 0, 0);
      }
      acc[nt] = c;
    }
    __syncthreads();

    float dvr[4];
    if (l == 2) {
#pragma unroll
      for (int r = 0; r < 4; ++r) {
        int grow = tile0 + wave * 16 + quad * 4 + r;
        dvr[r] = (grow < N) ? dinv[grow] : 0.f;
      }
    }

#pragma unroll
    for (int nt = 0; nt < 8; ++nt) {
      int n = nt * 16 + m16;
      float es = 1.f, eb = 0.f;
      if (l == 0) {
        float s = gamma[n] * rsqrtf(rvar[n] + 1e-5f);
        es = s; eb = s * (b1[n] - rmean[n]) + beta[n];
      } else if (l == 1) {
        eb = b2[n];
      }
#pragma unroll
      for (int r = 0; r < 4; ++r) {
        float v = acc[nt][r] * es + eb;
        if (l < 2) v = fmaxf(v, 0.f);
        else v *= dvr[r];
        H[wave * 16 + quad * 4 + r][n] = __float2bfloat16(v);
      }
    }
  }
  __syncthreads();

  {
    int row = t >> 2, c0 = (t & 3) * 32;
    int gr = tile0 + row;
    if (gr < N) {
      uint4* gp = (uint4*)(outb + (size_t)gr * DI + c0);
#pragma unroll
      for (int i = 0; i < 4; ++i)
        gp[i] = *(const uint4*)&H[row][c0 + i * 8];
    }
  }
}

// ---- GCN heads gather of pre-scaled y: out = bias + dinv_i * (y_i + sum y_j)
// rowbase layout: 32 lanes x 4 vals = 128 cols; cols 0-63 -> om, 64-127 -> ol.
// After the h-reduce, lane c4 owns cols 4c4..4c4+3.
__global__ __launch_bounds__(256) void k_aggr2(const uint2e* __restrict__ yb,
    const unsigned* __restrict__ rowptr, const unsigned* __restrict__ deg,
    const int* __restrict__ csr, const float* __restrict__ dinv,
    const float* __restrict__ bmu, const float* __restrict__ bls,
    float* __restrict__ om, float* __restrict__ ol, int N) {
  int gid = blockIdx.x * 256 + threadIdx.x;
  int w = gid >> 6, lane = gid & 63;
  if (w >= N) return;
  int h = lane >> 5, c4 = lane & 31;
  unsigned rowbase = (unsigned)w * 32u + (unsigned)c4;
  f32x4 a0 = {0.f, 0.f, 0.f, 0.f}, a1 = {0.f, 0.f, 0.f, 0.f};
  uint2e sv = yb[rowbase];
  if (h == 0) a0 = b4tof(sv);          // self: dinv_i * xw_i, pre-scaled
  unsigned start = rowptr[w];
  int cnt = (int)deg[w];
  for (int base = 0; base < cnt; base += 64) {
    int rem = cnt - base;
    int m = rem < 64 ? rem : 64;
    int idx = 0;
    if (lane < m)
      idx = __builtin_nontemporal_load(csr + start + base + lane);
    int j = 0;
    for (; j + 16 <= m; j += 16) {
      uint2e v[8];
#pragma unroll
      for (int u = 0; u < 8; ++u) {
        int s = __shfl(idx, j + 2 * u + h);
        v[u] = yb[(unsigned)s * 32u + (unsigned)c4];
      }
#pragma unroll
      for (int u = 0; u < 8; ++u) {
        if (u & 1) a1 += b4tof(v[u]); else a0 += b4tof(v[u]);
      }
    }
    if (j < m) {
      uint2e v[8];
#pragma unroll
      for (int u = 0; u < 8; ++u) {
        int ee = j + 2 * u + h;
        int s = __shfl(idx, ee < m ? ee : (m - 1));
        v[u] = yb[(unsigned)s * 32u + (unsigned)c4];
      }
#pragma unroll
      for (int u = 0; u < 8; ++u) {
        int ee = j + 2 * u + h;
        bool val = ee < m;
        v[u].x = val ? v[u].x : 0u;
        v[u].y = val ? v[u].y : 0u;
        if (u & 1) a1 += b4tof(v[u]); else a0 += b4tof(v[u]);
      }
    }
  }
  float di = dinv[w];
  a0 += a1;
#pragma unroll
  for (int k = 0; k < 4; ++k) a0[k] += __shfl_xor(a0[k], 32);
  if (h == 0) {
    const float* bsrc = (c4 < 16) ? (bmu + c4 * 4) : (bls + (c4 - 16) * 4);
    float* obase = (c4 < 16) ? (om + (size_t)w * 64 + c4 * 4)
                             : (ol + (size_t)w * 64 + (c4 - 16) * 4);
    f32x4 bb = *(const f32x4*)bsrc;
    f32x4 ov;
#pragma unroll
    for (int k = 0; k < 4; ++k) ov[k] = a0[k] * di + bb[k];
    __builtin_nontemporal_store(ov, (f32x4*)obase);
  }
}

extern "C" void kernel_launch(void* const* d_in, const int* in_sizes, int n_in,
                              void* d_out, int out_size, void* d_ws, size_t ws_size,
                              hipStream_t stream) {
  const float* x     = (const float*)d_in[0];
  const int*   ei    = (const int*)d_in[1];
  const float* W1    = (const float*)d_in[2];
  const float* b1    = (const float*)d_in[3];
  const float* gamma = (const float*)d_in[4];
  const float* beta  = (const float*)d_in[5];
  const float* rmean = (const float*)d_in[6];
  const float* rvar  = (const float*)d_in[7];
  const float* W2    = (const float*)d_in[8];
  const float* b2    = (const float*)d_in[9];
  const float* Wmu   = (const float*)d_in[10];
  const float* bmu   = (const float*)d_in[11];
  const float* Wls   = (const float*)d_in[12];
  const float* bls   = (const float*)d_in[13];

  int N = in_sizes[0] / 128;
  int E = in_sizes[1] / 2;
  const int* src = ei;
  const int* dst = ei + E;
  int nb = (N + 255) / 256;

  char* ws = (char*)d_ws;
  size_t off = 0;
  __hip_bfloat16* xb   = (__hip_bfloat16*)(ws + off); off += (size_t)N * DI * 2;  // reused as y
  __hip_bfloat16* bufb = (__hip_bfloat16*)(ws + off); off += (size_t)N * DI * 2;
  unsigned* deg    = (unsigned*)(ws + off); off += (size_t)N * 4;
  unsigned* part   = (unsigned*)(ws + off); off += (size_t)N * 4;
  unsigned* rowptr = (unsigned*)(ws + off); off += (size_t)N * 4;
  float*    dinv   = (float*)(ws + off); off += (size_t)N * 4;
  unsigned* bsum   = (unsigned*)(ws + off); off += (size_t)((nb + 255) & ~255) * 4;
  __hip_bfloat16* Wt3 = (__hip_bfloat16*)(ws + off); off += 3 * 16384 * 2;
  unsigned short* rank = (unsigned short*)(ws + off); off += (size_t)E * 2;
  int* csr_src     = (int*)(ws + off); off += (size_t)E * 4;

  float* om = (float*)d_out;
  float* ol = om + (size_t)N * 64;

  int tiles = (N + 63) / 64;
  int nodeBlocks = (N * 64 + 255) / 256;
  int tot8 = N * 16;
  int cvtB = (tot8 + 255) / 256;
  int prepB = nb + cvtB + 192;
  int E2 = E / 2;

  k_prep <<<prepB, 256, 0, stream>>>(deg, N, nb, (const float4*)x, (uint4*)xb,
                                     tot8, cvtB, W1, W2, Wmu, Wls, Wt3);
  k_count<<<(E2 + 255) / 256, 256, 0, stream>>>((const int2e*)dst, deg,
                                                (unsigned*)rank, E2);
  k_scan1<<<nb, 256, 0, stream>>>(deg, part, bsum, N);
  k_scan2<<<1, 256, 0, stream>>>(bsum, nb);
  k_scan3<<<nb, 256, 0, stream>>>(part, bsum, deg, rowptr, dinv, N);
  k_fillp<<<2048, 256, 0, stream>>>(src, (const int4e*)dst, rank, rowptr,
                                    csr_src, E, N);
  k_aggr1<<<nodeBlocks, 256, 0, stream>>>((const uint2e*)xb, rowptr, deg,
                                          csr_src, (uint2e*)bufb, N);
  k_mlp  <<<tiles, 256, 0, stream>>>(bufb, Wt3, b1, gamma, beta, rmean, rvar, b2,
                                     dinv, xb /* y out, reuse */, N);
  k_aggr2<<<nodeBlocks, 256, 0, stream>>>((const uint2e*)xb, rowptr, deg,
                                          csr_src, dinv, bmu, bls, om, ol, N);
}